// Round 2
// baseline (210.804 us; speedup 1.0000x reference)
//
#include <hip/hip_runtime.h>
#include <cmath>
#include <cstdint>

#define N_NODES 100000
#define SAMPLES 16
#define DIM 128
#define NBATCH 8192

#define FSTR 264    // f16 LDS row stride (256 + 8 pad)
#define H2STR 132   // fp32 LDS row stride for layer2 h2 staging

typedef _Float16 half8 __attribute__((ext_vector_type(8)));
typedef float floatx4 __attribute__((ext_vector_type(4)));
typedef int intx4 __attribute__((ext_vector_type(4)));

__device__ __forceinline__ half8 h8max(half8 a, half8 b) {
    half8 r;
#pragma unroll
    for (int i = 0; i < 8; ++i) r[i] = (a[i] > b[i]) ? a[i] : b[i];
    return r;
}

// Fused setup: cvt_x (chunk-major) [0,6250) | swizzle_w [6250,6282) | mark_flags [6282,6314)
// flags semantics: "flagged" == (flags[i] == 1); d_ws arrives 0xAA-poisoned so
// no zero pass is needed (garbage != 1; accidental 1 only adds work, never drops).
//
// xc layout is CHUNK-MAJOR: xc[c][node][16] f16, c in [0,8). Chunk c of every
// node is a contiguous 3.2 MB region -> one chunk fits a per-XCD 4 MiB L2.
__global__ __launch_bounds__(256) void setup_kernel(
    const float* __restrict__ x,
    const float* __restrict__ W1,
    const float* __restrict__ W2,
    const int* __restrict__ batch,
    const int* __restrict__ nidx,
    int* __restrict__ flags,
    _Float16* __restrict__ xc,
    _Float16* __restrict__ W1sw,
    _Float16* __restrict__ W2sw) {
    const int bid = blockIdx.x;
    if (bid < 6250) {
        const int tid = bid * 256 + threadIdx.x;   // 16 threads per 128-f row
        const int node = tid >> 4;
        const int cl = tid & 15;                   // 16B chunk within row
        const size_t base = (size_t)tid * 8;       // == node*128 + cl*8
        const float4* xp = (const float4*)(x + base);
        const float4 a = xp[0], b = xp[1];
        half8 v;
        v[0] = (_Float16)a.x; v[1] = (_Float16)a.y;
        v[2] = (_Float16)a.z; v[3] = (_Float16)a.w;
        v[4] = (_Float16)b.x; v[5] = (_Float16)b.y;
        v[6] = (_Float16)b.z; v[7] = (_Float16)b.w;
        // chunk-major store: c = cl>>1 (32B chunk), h = cl&1 (16B half).
        // Per wave: for fixed c, 8 lanes cover 4 consecutive nodes -> 128B segs.
        const int c = cl >> 1, h = cl & 1;
        *(half8*)(xc + (size_t)c * (N_NODES * 16) + (size_t)node * 16 + h * 8) = v;
    } else if (bid < 6282) {
        // W[256][128] -> f16 B-fragment order for mfma_f32_16x16x32_f16:
        // frag (kb,nb,lane): B[k=kb*32+(lane>>4)*8+j][n=nb*16+(lane&15)]
        const int tid = (bid - 6250) * 256 + threadIdx.x;  // [0, 8192)
        const int which = tid >> 12;
        const int r = tid & 4095;
        const int kb = r >> 9, nb = (r >> 6) & 7, lane = r & 63;
        const int q = lane >> 4, c = lane & 15;
        const float* W = which ? W2 : W1;
        _Float16* O = which ? W2sw : W1sw;
        const int k0 = kb * 32 + q * 8;
        const int n = nb * 16 + c;
        half8 v;
#pragma unroll
        for (int j = 0; j < 8; ++j) v[j] = (_Float16)W[(size_t)(k0 + j) * DIM + n];
        *(half8*)(O + (size_t)r * 8) = v;
    } else {
        const int j = (bid - 6282) * 256 + threadIdx.x;
        if (j < NBATCH) {
            const int b = batch[j];
            flags[b] = 1;
            const int* row = nidx + (size_t)b * SAMPLES;
#pragma unroll
            for (int s = 0; s < SAMPLES; ++s) flags[row[s]] = 1;
        }
    }
}

// XCD-partitioned neighbor gather+max for layer1.
// Grid = 8 chunks x 782 node-tiles, bid = tile*8 + chunk so chunk == bid%8 ==
// the XCD this block lands on (round-robin dispatch). Each XCD then only ever
// reads ONE 3.2 MB chunk region of xc -> resident in its private 4 MiB L2, so
// the ~330 MB of 12x-re-read gather traffic is served from L2, not L3/HBM.
// nidx (re-read 8x) and the agg output are NONTEMPORAL so they stream through
// without evicting the chunk.
// 2 lanes per node (h = 16B half of the 32B chunk); 16 neighbor loads in
// flight per lane (no reduction-tree register reuse pressure: no LDS, no MFMA
// in this kernel, so VGPRs are free for full memory-level parallelism).
__global__ __launch_bounds__(256) void gather1_kernel(
    const _Float16* __restrict__ xc,
    const int* __restrict__ nidx,
    const int* __restrict__ flags,
    _Float16* __restrict__ agg) {
    const int bid = blockIdx.x;
    const int c = bid & 7;          // chunk == XCD
    const int tile = bid >> 3;
    const int t = threadIdx.x;
    const int nl = t >> 1, h = t & 1;
    const int node = tile * 128 + nl;
    if (node >= N_NODES) return;
    if (flags[node] != 1) return;

    const _Float16* xcc = xc + (size_t)c * (N_NODES * 16) + h * 8;
    const intx4* ip = (const intx4*)(nidx + (size_t)node * SAMPLES);
    const intx4 a0 = __builtin_nontemporal_load(ip);
    const intx4 a1 = __builtin_nontemporal_load(ip + 1);
    const intx4 a2 = __builtin_nontemporal_load(ip + 2);
    const intx4 a3 = __builtin_nontemporal_load(ip + 3);

    half8 v[16];
    v[0]  = *(const half8*)(xcc + a0[0] * 16);
    v[1]  = *(const half8*)(xcc + a0[1] * 16);
    v[2]  = *(const half8*)(xcc + a0[2] * 16);
    v[3]  = *(const half8*)(xcc + a0[3] * 16);
    v[4]  = *(const half8*)(xcc + a1[0] * 16);
    v[5]  = *(const half8*)(xcc + a1[1] * 16);
    v[6]  = *(const half8*)(xcc + a1[2] * 16);
    v[7]  = *(const half8*)(xcc + a1[3] * 16);
    v[8]  = *(const half8*)(xcc + a2[0] * 16);
    v[9]  = *(const half8*)(xcc + a2[1] * 16);
    v[10] = *(const half8*)(xcc + a2[2] * 16);
    v[11] = *(const half8*)(xcc + a2[3] * 16);
    v[12] = *(const half8*)(xcc + a3[0] * 16);
    v[13] = *(const half8*)(xcc + a3[1] * 16);
    v[14] = *(const half8*)(xcc + a3[2] * 16);
    v[15] = *(const half8*)(xcc + a3[3] * 16);
#pragma unroll
    for (int s = 0; s < 8; ++s) v[s] = h8max(v[s], v[s + 8]);
#pragma unroll
    for (int s = 0; s < 4; ++s) v[s] = h8max(v[s], v[s + 4]);
    const half8 mx = h8max(h8max(v[0], v[1]), h8max(v[2], v[3]));

    // agg is row-major [node][128] (it aliases h1h; see layer1_mm). nt store:
    // consumed once by layer1_mm from L3/HBM; must NOT evict xc from this L2.
    __builtin_nontemporal_store(mx, (half8*)(agg + (size_t)node * DIM + c * 16 + h * 8));
}

// layer1 matmul: self (chunk-major xc, coalesced) + agg (row-major) -> LDS
// feats -> MFMA with pre-swizzled W1 -> bias+relu -> h1h.
// aggh is BOTH the agg input and the h1h output (same [node][128] f16 layout):
// each block reads its 16 rows into LDS before __syncthreads, and only its own
// rows are overwritten in the epilogue -> no inter-block hazard, and it keeps
// the workspace footprint identical to the previous version.
__global__ __launch_bounds__(256) void layer1_mm_kernel(
    const _Float16* __restrict__ xc,
    const _Float16* __restrict__ W1sw,
    const float* __restrict__ b1,
    const int* __restrict__ flags,
    _Float16* aggh) {
    const int t = threadIdx.x;
    const int g = t >> 4;        // node slot 0..15
    const int cl = t & 15;       // 16B chunk 0..15
    const int i0 = blockIdx.x * 16;
    const int i = i0 + g;        // 6250*16 == 100000 exactly

    __shared__ __align__(16) _Float16 feats[16 * FSTR];

    const bool fi = (flags[i] == 1);
    if (fi) {
        const int c = cl >> 1, h = cl & 1;
        const half8 self = *(const half8*)(xc + (size_t)c * (N_NODES * 16) + (size_t)i * 16 + h * 8);
        const half8 mx = *(const half8*)(aggh + (size_t)i * DIM + cl * 8);
        *(half8*)(feats + g * FSTR + cl * 8) = self;
        *(half8*)(feats + g * FSTR + DIM + cl * 8) = mx;
    } else {
        half8 z;
#pragma unroll
        for (int e = 0; e < 8; ++e) z[e] = (_Float16)0.f;
        *(half8*)(feats + g * FSTR + cl * 8) = z;
        *(half8*)(feats + g * FSTR + DIM + cl * 8) = z;
    }
    __syncthreads();

    // MFMA: wave w computes nb = 2w, 2w+1 over K=256.
    // A[m=c][k=kb*32+q*8+j] from LDS; B from pre-swizzled W1; D[m=q*4+r][n=nb*16+c]
    const int wave = t >> 6;
    const int lane = t & 63;
    const int q = lane >> 4, c = lane & 15;
    const int nb0 = wave * 2;
    floatx4 acc[2];
    acc[0] = (floatx4){0.f, 0.f, 0.f, 0.f};
    acc[1] = (floatx4){0.f, 0.f, 0.f, 0.f};
#pragma unroll
    for (int kb = 0; kb < 8; ++kb) {
        const half8 a = *(const half8*)(feats + c * FSTR + kb * 32 + q * 8);
#pragma unroll
        for (int j = 0; j < 2; ++j) {
            const half8 b = *(const half8*)(W1sw + (size_t)((kb * 8 + nb0 + j) * 64 + lane) * 8);
            acc[j] = __builtin_amdgcn_mfma_f32_16x16x32_f16(a, b, acc[j], 0, 0, 0);
        }
    }

    // epilogue: bias + relu + non-temporal f16 store, gated per stored row
#pragma unroll
    for (int r = 0; r < 4; ++r) {
        const int node = i0 + q * 4 + r;
        if (flags[node] != 1) continue;
#pragma unroll
        for (int j = 0; j < 2; ++j) {
            const int n = (nb0 + j) * 16 + c;
            const float v = fmaxf(acc[j][r] + b1[n], 0.f);
            const _Float16 hv = (_Float16)v;
            __builtin_nontemporal_store(hv, aggh + (size_t)node * DIM + n);
        }
    }
}

// Cooperative layer2: 256 threads / 16 batch rows; gather + MFMA + fused proj_out.
__global__ __launch_bounds__(256) void layer2_kernel(
    const _Float16* __restrict__ h1h,
    const int* __restrict__ nidx,
    const int* __restrict__ batch,
    const _Float16* __restrict__ W2sw,
    const float* __restrict__ b2,
    const float* __restrict__ Wout,
    const float* __restrict__ bout,
    float* __restrict__ out) {
    const int t = threadIdx.x;
    const int wave = t >> 6;
    const int lane = t & 63;
    const int q = lane >> 4, c = lane & 15;
    const int w0 = blockIdx.x * 16;

    __shared__ __align__(16) _Float16 feats[16 * FSTR];
    __shared__ __align__(16) float h2s[16 * H2STR];

    // ---- gather ----
    {
        const int m = t >> 4;
        const int cl = t & 15;
        const int node = batch[w0 + m];
        const char* hb = (const char*)h1h;
        const int cb = cl * 16;
        const half8 self = *(const half8*)(hb + (size_t)node * 256 + cb);
        const int4* ip = (const int4*)(nidx + (size_t)node * SAMPLES);
        const int4 a0 = ip[0], a1 = ip[1], a2 = ip[2], a3 = ip[3];
        int off[16];
        off[0]  = a0.x * 256 + cb; off[1]  = a0.y * 256 + cb;
        off[2]  = a0.z * 256 + cb; off[3]  = a0.w * 256 + cb;
        off[4]  = a1.x * 256 + cb; off[5]  = a1.y * 256 + cb;
        off[6]  = a1.z * 256 + cb; off[7]  = a1.w * 256 + cb;
        off[8]  = a2.x * 256 + cb; off[9]  = a2.y * 256 + cb;
        off[10] = a2.z * 256 + cb; off[11] = a2.w * 256 + cb;
        off[12] = a3.x * 256 + cb; off[13] = a3.y * 256 + cb;
        off[14] = a3.z * 256 + cb; off[15] = a3.w * 256 + cb;
        half8 v[16];
#pragma unroll
        for (int s = 0; s < 16; ++s) v[s] = *(const half8*)(hb + off[s]);
#pragma unroll
        for (int s = 0; s < 8; ++s) v[s] = h8max(v[s], v[s + 8]);
#pragma unroll
        for (int s = 0; s < 4; ++s) v[s] = h8max(v[s], v[s + 4]);
        const half8 mx = h8max(h8max(v[0], v[1]), h8max(v[2], v[3]));
        *(half8*)(feats + m * FSTR + cl * 8) = self;
        *(half8*)(feats + m * FSTR + DIM + cl * 8) = mx;
    }
    __syncthreads();

    // ---- MFMA: wave computes nb = 2*wave, 2*wave+1 over K=256 ----
    const int nb0 = wave * 2;
    floatx4 acc[2];
    acc[0] = (floatx4){0.f, 0.f, 0.f, 0.f};
    acc[1] = (floatx4){0.f, 0.f, 0.f, 0.f};
#pragma unroll
    for (int kb = 0; kb < 8; ++kb) {
        const half8 a = *(const half8*)(feats + c * FSTR + kb * 32 + q * 8);
#pragma unroll
        for (int j = 0; j < 2; ++j) {
            const half8 b = *(const half8*)(W2sw + (size_t)((kb * 8 + nb0 + j) * 64 + lane) * 8);
            acc[j] = __builtin_amdgcn_mfma_f32_16x16x32_f16(a, b, acc[j], 0, 0, 0);
        }
    }
#pragma unroll
    for (int j = 0; j < 2; ++j) {
        const int n = (nb0 + j) * 16 + c;
        const float bias = b2[n];
#pragma unroll
        for (int r = 0; r < 4; ++r)
            h2s[(q * 4 + r) * H2STR + n] = acc[j][r] + bias;
    }
    __syncthreads();

    // ---- proj_out: wave handles rows wave*4..+3; lane = output dim ----
    float accs[4];
    const float bo = bout[lane];
#pragma unroll
    for (int r = 0; r < 4; ++r) accs[r] = bo;
    for (int k4 = 0; k4 < DIM; k4 += 4) {
        float wv[4];
#pragma unroll
        for (int j = 0; j < 4; ++j) wv[j] = Wout[(size_t)(k4 + j) * 64 + lane];
#pragma unroll
        for (int r = 0; r < 4; ++r) {
            const float4 f = *(const float4*)&h2s[(wave * 4 + r) * H2STR + k4];
            accs[r] += f.x * wv[0] + f.y * wv[1] + f.z * wv[2] + f.w * wv[3];
        }
    }
#pragma unroll
    for (int r = 0; r < 4; ++r)
        __builtin_nontemporal_store(accs[r], out + (size_t)(w0 + wave * 4 + r) * 64 + lane);
}

extern "C" void kernel_launch(void* const* d_in, const int* in_sizes, int n_in,
                              void* d_out, int out_size, void* d_ws, size_t ws_size,
                              hipStream_t stream) {
    const float* x    = (const float*)d_in[0];
    const int* nidx   = (const int*)d_in[1];
    const int* batch  = (const int*)d_in[2];
    const float* W1   = (const float*)d_in[3];
    const float* b1   = (const float*)d_in[4];
    const float* W2   = (const float*)d_in[5];
    const float* b2   = (const float*)d_in[6];
    const float* Wout = (const float*)d_in[7];
    const float* bout = (const float*)d_in[8];
    float* out        = (float*)d_out;

    // ws layout (bytes):
    //   [0, 400000)           flags (poison-based: flagged == 1)
    //   [409600, 475136)      W1sw f16
    //   [475136, 540672)      W2sw f16
    //   [540672, 26140672)    xc    f16  chunk-major [8][N_NODES][16]
    //   [26140672, 51740672)  agg/h1h f16 row-major [N_NODES][128] (aliased)
    int* flags      = (int*)d_ws;
    _Float16* W1sw  = (_Float16*)((char*)d_ws + 409600);
    _Float16* W2sw  = (_Float16*)((char*)d_ws + 475136);
    _Float16* xc    = (_Float16*)((char*)d_ws + 540672);
    _Float16* aggh  = (_Float16*)((char*)d_ws + 26140672);

    setup_kernel<<<6314, 256, 0, stream>>>(x, W1, W2, batch, nidx, flags, xc, W1sw, W2sw);
    gather1_kernel<<<782 * 8, 256, 0, stream>>>(xc, nidx, flags, aggh);
    layer1_mm_kernel<<<N_NODES / 16, 256, 0, stream>>>(xc, W1sw, b1, flags, aggh);
    layer2_kernel<<<NBATCH / 16, 256, 0, stream>>>(aggh, nidx, batch, W2sw, b2, Wout, bout, out);
}

// Round 3
// 171.263 us; speedup vs baseline: 1.2309x; 1.2309x over previous
//
#include <hip/hip_runtime.h>
#include <cmath>
#include <cstdint>

#define N_NODES 100000
#define SAMPLES 16
#define DIM 128
#define NBATCH 8192

#define FSTR 264    // f16 LDS row stride (256 + 8 pad)
#define H2STR 132   // fp32 LDS row stride for layer2 h2 staging

typedef _Float16 half8 __attribute__((ext_vector_type(8)));
typedef float floatx4 __attribute__((ext_vector_type(4)));

__device__ __forceinline__ half8 h8max(half8 a, half8 b) {
    half8 r;
#pragma unroll
    for (int i = 0; i < 8; ++i) r[i] = (a[i] > b[i]) ? a[i] : b[i];
    return r;
}

// Fused setup: cvt_x [0,6250) | swizzle_w [6250,6282) | mark_flags [6282,6314)
// flags semantics: "flagged" == (flags[i] == 1); d_ws arrives 0xAA-poisoned so
// no zero pass is needed (garbage != 1; accidental 1 only adds work, never drops).
__global__ __launch_bounds__(256) void setup_kernel(
    const float* __restrict__ x,
    const float* __restrict__ W1,
    const float* __restrict__ W2,
    const int* __restrict__ batch,
    const int* __restrict__ nidx,
    int* __restrict__ flags,
    _Float16* __restrict__ xh,
    _Float16* __restrict__ W1sw,
    _Float16* __restrict__ W2sw) {
    const int bid = blockIdx.x;
    if (bid < 6250) {
        const size_t base = ((size_t)bid * 256 + threadIdx.x) * 8;
        const float4* xp = (const float4*)(x + base);
        const float4 a = xp[0], b = xp[1];
        half8 v;
        v[0] = (_Float16)a.x; v[1] = (_Float16)a.y;
        v[2] = (_Float16)a.z; v[3] = (_Float16)a.w;
        v[4] = (_Float16)b.x; v[5] = (_Float16)b.y;
        v[6] = (_Float16)b.z; v[7] = (_Float16)b.w;
        *(half8*)(xh + base) = v;
    } else if (bid < 6282) {
        // W[256][128] -> f16 B-fragment order for mfma_f32_16x16x32_f16:
        // frag (kb,nb,lane): B[k=kb*32+(lane>>4)*8+j][n=nb*16+(lane&15)]
        const int tid = (bid - 6250) * 256 + threadIdx.x;  // [0, 8192)
        const int which = tid >> 12;
        const int r = tid & 4095;
        const int kb = r >> 9, nb = (r >> 6) & 7, lane = r & 63;
        const int q = lane >> 4, c = lane & 15;
        const float* W = which ? W2 : W1;
        _Float16* O = which ? W2sw : W1sw;
        const int k0 = kb * 32 + q * 8;
        const int n = nb * 16 + c;
        half8 v;
#pragma unroll
        for (int j = 0; j < 8; ++j) v[j] = (_Float16)W[(size_t)(k0 + j) * DIM + n];
        *(half8*)(O + (size_t)r * 8) = v;
    } else {
        const int j = (bid - 6282) * 256 + threadIdx.x;
        if (j < NBATCH) {
            const int b = batch[j];
            flags[b] = 1;
            const int* row = nidx + (size_t)b * SAMPLES;
#pragma unroll
            for (int s = 0; s < SAMPLES; ++s) flags[row[s]] = 1;
        }
    }
}

// layer1 (round-0 structure + sorted-trickle gather): block = 256 threads =
// 16 nodes. 16-lane group g gathers node blockIdx*16+g, lane cl = one 16B
// chunk of the 256B row -> full-row coalesced reads.
//
// Sorted-trickle: each lane sorts the 16 neighbor indices with a Batcher
// odd-even merge network (registers only; a CE network is always a
// permutation, and max is order-invariant -> correctness unconditional).
// Loads then issue in ASCENDING-address order as 8 batches of 2, fenced by
// sched_barrier(0) so the compiler cannot hoist them into one 16-deep burst.
// All waves chip-wide therefore walk xh bottom-up in rough lockstep: at any
// instant the in-flight gather addresses cluster in a ~3 MB band -> each
// XCD's 4 MiB L2 holds the band -> the ~12x re-reads hit L2 (~300cy) instead
// of L3 (~800cy). TLP (12+ waves/CU) covers the per-wave serialization.
__global__ __launch_bounds__(256) void layer1_kernel(
    const _Float16* __restrict__ xh,
    const int* __restrict__ nidx,
    const _Float16* __restrict__ W1sw,
    const float* __restrict__ b1,
    const int* __restrict__ flags,
    _Float16* __restrict__ h1h) {
    const int t = threadIdx.x;
    const int g = t >> 4;        // node slot 0..15
    const int cl = t & 15;       // 16B chunk 0..15
    const int i0 = blockIdx.x * 16;
    const int i = i0 + g;        // 6250*16 == 100000 exactly

    __shared__ __align__(16) _Float16 feats[16 * FSTR];

    const bool fi = (flags[i] == 1);
    if (fi) {
        const char* xb = (const char*)xh;
        const int cb = cl * 16;
        const half8 self = *(const half8*)(xb + (size_t)i * 256 + cb);
        const int4* ip = (const int4*)(nidx + (size_t)i * SAMPLES);
        const int4 a0 = ip[0], a1 = ip[1], a2 = ip[2], a3 = ip[3];
        int srt[16];
        srt[0]  = a0.x; srt[1]  = a0.y; srt[2]  = a0.z; srt[3]  = a0.w;
        srt[4]  = a1.x; srt[5]  = a1.y; srt[6]  = a1.z; srt[7]  = a1.w;
        srt[8]  = a2.x; srt[9]  = a2.y; srt[10] = a2.z; srt[11] = a2.w;
        srt[12] = a3.x; srt[13] = a3.y; srt[14] = a3.z; srt[15] = a3.w;
        // Batcher odd-even mergesort, n=16, fully unrolled (63 CEs, all
        // indices compile-time constant -> stays in VGPRs).
#pragma unroll
        for (int p = 1; p < 16; p <<= 1) {
#pragma unroll
            for (int k = p; k >= 1; k >>= 1) {
#pragma unroll
                for (int j = k % p; j <= 15 - k; j += 2 * k) {
#pragma unroll
                    for (int ii = 0; ii < k; ++ii) {
                        if (ii + j + k <= 15 &&
                            (ii + j) / (2 * p) == (ii + j + k) / (2 * p)) {
                            const int u = srt[ii + j], w = srt[ii + j + k];
                            srt[ii + j] = u < w ? u : w;
                            srt[ii + j + k] = u < w ? w : u;
                        }
                    }
                }
            }
        }
        int off[16];
#pragma unroll
        for (int s = 0; s < 16; ++s) off[s] = srt[s] * 256 + cb;
        // trickle: 2 loads in flight per lane, ascending address order
        half8 v0 = *(const half8*)(xb + off[0]);
        half8 v1 = *(const half8*)(xb + off[1]);
        half8 acc = h8max(v0, v1);
#pragma unroll
        for (int bp = 1; bp < 8; ++bp) {
            __builtin_amdgcn_sched_barrier(0);
            const half8 w0 = *(const half8*)(xb + off[2 * bp]);
            const half8 w1 = *(const half8*)(xb + off[2 * bp + 1]);
            acc = h8max(acc, h8max(w0, w1));
        }
        *(half8*)(feats + g * FSTR + cl * 8) = self;
        *(half8*)(feats + g * FSTR + DIM + cl * 8) = acc;
    } else {
        half8 z;
#pragma unroll
        for (int e = 0; e < 8; ++e) z[e] = (_Float16)0.f;
        *(half8*)(feats + g * FSTR + cl * 8) = z;
        *(half8*)(feats + g * FSTR + DIM + cl * 8) = z;
    }
    __syncthreads();

    // MFMA: wave w computes nb = 2w, 2w+1 over K=256.
    // A[m=c][k=kb*32+q*8+j] from LDS; B from pre-swizzled W1; D[m=q*4+r][n=nb*16+c]
    const int wave = t >> 6;
    const int lane = t & 63;
    const int q = lane >> 4, c = lane & 15;
    const int nb0 = wave * 2;
    floatx4 acc[2];
    acc[0] = (floatx4){0.f, 0.f, 0.f, 0.f};
    acc[1] = (floatx4){0.f, 0.f, 0.f, 0.f};
#pragma unroll
    for (int kb = 0; kb < 8; ++kb) {
        const half8 a = *(const half8*)(feats + c * FSTR + kb * 32 + q * 8);
#pragma unroll
        for (int j = 0; j < 2; ++j) {
            const half8 b = *(const half8*)(W1sw + (size_t)((kb * 8 + nb0 + j) * 64 + lane) * 8);
            acc[j] = __builtin_amdgcn_mfma_f32_16x16x32_f16(a, b, acc[j], 0, 0, 0);
        }
    }

    // epilogue: bias + relu + non-temporal f16 store, gated per stored row
#pragma unroll
    for (int r = 0; r < 4; ++r) {
        const int node = i0 + q * 4 + r;
        if (flags[node] != 1) continue;
#pragma unroll
        for (int j = 0; j < 2; ++j) {
            const int n = (nb0 + j) * 16 + c;
            const float v = fmaxf(acc[j][r] + b1[n], 0.f);
            const _Float16 hv = (_Float16)v;
            __builtin_nontemporal_store(hv, h1h + (size_t)node * DIM + n);
        }
    }
}

// Cooperative layer2: 256 threads / 16 batch rows; gather + MFMA + fused proj_out.
__global__ __launch_bounds__(256) void layer2_kernel(
    const _Float16* __restrict__ h1h,
    const int* __restrict__ nidx,
    const int* __restrict__ batch,
    const _Float16* __restrict__ W2sw,
    const float* __restrict__ b2,
    const float* __restrict__ Wout,
    const float* __restrict__ bout,
    float* __restrict__ out) {
    const int t = threadIdx.x;
    const int wave = t >> 6;
    const int lane = t & 63;
    const int q = lane >> 4, c = lane & 15;
    const int w0 = blockIdx.x * 16;

    __shared__ __align__(16) _Float16 feats[16 * FSTR];
    __shared__ __align__(16) float h2s[16 * H2STR];

    // ---- gather ----
    {
        const int m = t >> 4;
        const int cl = t & 15;
        const int node = batch[w0 + m];
        const char* hb = (const char*)h1h;
        const int cb = cl * 16;
        const half8 self = *(const half8*)(hb + (size_t)node * 256 + cb);
        const int4* ip = (const int4*)(nidx + (size_t)node * SAMPLES);
        const int4 a0 = ip[0], a1 = ip[1], a2 = ip[2], a3 = ip[3];
        int off[16];
        off[0]  = a0.x * 256 + cb; off[1]  = a0.y * 256 + cb;
        off[2]  = a0.z * 256 + cb; off[3]  = a0.w * 256 + cb;
        off[4]  = a1.x * 256 + cb; off[5]  = a1.y * 256 + cb;
        off[6]  = a1.z * 256 + cb; off[7]  = a1.w * 256 + cb;
        off[8]  = a2.x * 256 + cb; off[9]  = a2.y * 256 + cb;
        off[10] = a2.z * 256 + cb; off[11] = a2.w * 256 + cb;
        off[12] = a3.x * 256 + cb; off[13] = a3.y * 256 + cb;
        off[14] = a3.z * 256 + cb; off[15] = a3.w * 256 + cb;
        half8 v[16];
#pragma unroll
        for (int s = 0; s < 16; ++s) v[s] = *(const half8*)(hb + off[s]);
#pragma unroll
        for (int s = 0; s < 8; ++s) v[s] = h8max(v[s], v[s + 8]);
#pragma unroll
        for (int s = 0; s < 4; ++s) v[s] = h8max(v[s], v[s + 4]);
        const half8 mx = h8max(h8max(v[0], v[1]), h8max(v[2], v[3]));
        *(half8*)(feats + m * FSTR + cl * 8) = self;
        *(half8*)(feats + m * FSTR + DIM + cl * 8) = mx;
    }
    __syncthreads();

    // ---- MFMA: wave computes nb = 2*wave, 2*wave+1 over K=256 ----
    const int nb0 = wave * 2;
    floatx4 acc[2];
    acc[0] = (floatx4){0.f, 0.f, 0.f, 0.f};
    acc[1] = (floatx4){0.f, 0.f, 0.f, 0.f};
#pragma unroll
    for (int kb = 0; kb < 8; ++kb) {
        const half8 a = *(const half8*)(feats + c * FSTR + kb * 32 + q * 8);
#pragma unroll
        for (int j = 0; j < 2; ++j) {
            const half8 b = *(const half8*)(W2sw + (size_t)((kb * 8 + nb0 + j) * 64 + lane) * 8);
            acc[j] = __builtin_amdgcn_mfma_f32_16x16x32_f16(a, b, acc[j], 0, 0, 0);
        }
    }
#pragma unroll
    for (int j = 0; j < 2; ++j) {
        const int n = (nb0 + j) * 16 + c;
        const float bias = b2[n];
#pragma unroll
        for (int r = 0; r < 4; ++r)
            h2s[(q * 4 + r) * H2STR + n] = acc[j][r] + bias;
    }
    __syncthreads();

    // ---- proj_out: wave handles rows wave*4..+3; lane = output dim ----
    float accs[4];
    const float bo = bout[lane];
#pragma unroll
    for (int r = 0; r < 4; ++r) accs[r] = bo;
    for (int k4 = 0; k4 < DIM; k4 += 4) {
        float wv[4];
#pragma unroll
        for (int j = 0; j < 4; ++j) wv[j] = Wout[(size_t)(k4 + j) * 64 + lane];
#pragma unroll
        for (int r = 0; r < 4; ++r) {
            const float4 f = *(const float4*)&h2s[(wave * 4 + r) * H2STR + k4];
            accs[r] += f.x * wv[0] + f.y * wv[1] + f.z * wv[2] + f.w * wv[3];
        }
    }
#pragma unroll
    for (int r = 0; r < 4; ++r)
        __builtin_nontemporal_store(accs[r], out + (size_t)(w0 + wave * 4 + r) * 64 + lane);
}

extern "C" void kernel_launch(void* const* d_in, const int* in_sizes, int n_in,
                              void* d_out, int out_size, void* d_ws, size_t ws_size,
                              hipStream_t stream) {
    const float* x    = (const float*)d_in[0];
    const int* nidx   = (const int*)d_in[1];
    const int* batch  = (const int*)d_in[2];
    const float* W1   = (const float*)d_in[3];
    const float* b1   = (const float*)d_in[4];
    const float* W2   = (const float*)d_in[5];
    const float* b2   = (const float*)d_in[6];
    const float* Wout = (const float*)d_in[7];
    const float* bout = (const float*)d_in[8];
    float* out        = (float*)d_out;

    // ws layout (bytes):
    //   [0, 400000)           flags (poison-based: flagged == 1)
    //   [409600, 475136)      W1sw f16
    //   [475136, 540672)      W2sw f16
    //   [540672, 26140672)    xh   f16
    //   [26140672, 51740672)  h1h  f16
    int* flags      = (int*)d_ws;
    _Float16* W1sw  = (_Float16*)((char*)d_ws + 409600);
    _Float16* W2sw  = (_Float16*)((char*)d_ws + 475136);
    _Float16* xh    = (_Float16*)((char*)d_ws + 540672);
    _Float16* h1h   = (_Float16*)((char*)d_ws + 26140672);

    setup_kernel<<<6314, 256, 0, stream>>>(x, W1, W2, batch, nidx, flags, xh, W1sw, W2sw);
    layer1_kernel<<<N_NODES / 16, 256, 0, stream>>>(xh, nidx, W1sw, b1, flags, h1h);
    layer2_kernel<<<NBATCH / 16, 256, 0, stream>>>(h1h, nidx, batch, W2sw, b2, Wout, bout, out);
}

// Round 4
// 170.080 us; speedup vs baseline: 1.2394x; 1.0070x over previous
//
#include <hip/hip_runtime.h>
#include <cmath>
#include <cstdint>

#define N_NODES 100000
#define SAMPLES 16
#define DIM 128
#define NBATCH 8192

#define FSTR 264    // f16 LDS row stride (256 + 8 pad)
#define H2STR 132   // fp32 LDS row stride for layer2 h2 staging

typedef _Float16 half8 __attribute__((ext_vector_type(8)));
typedef _Float16 half4 __attribute__((ext_vector_type(4)));
typedef float floatx4 __attribute__((ext_vector_type(4)));

__device__ __forceinline__ half8 h8max(half8 a, half8 b) {
    half8 r;
#pragma unroll
    for (int i = 0; i < 8; ++i) r[i] = (a[i] > b[i]) ? a[i] : b[i];
    return r;
}

__device__ __forceinline__ half4 h4max(half4 a, half4 b) {
    half4 r;
#pragma unroll
    for (int i = 0; i < 4; ++i) r[i] = (a[i] > b[i]) ? a[i] : b[i];
    return r;
}

// Fused setup: cvt_x [0,6250) | swizzle_w [6250,6282) | mark_flags [6282,6314)
// flags semantics: "flagged" == (flags[i] == 1); d_ws arrives 0xAA-poisoned so
// no zero pass is needed (garbage != 1; accidental 1 only adds work, never drops).
__global__ __launch_bounds__(256) void setup_kernel(
    const float* __restrict__ x,
    const float* __restrict__ W1,
    const float* __restrict__ W2,
    const int* __restrict__ batch,
    const int* __restrict__ nidx,
    int* __restrict__ flags,
    _Float16* __restrict__ xh,
    _Float16* __restrict__ W1sw,
    _Float16* __restrict__ W2sw) {
    const int bid = blockIdx.x;
    if (bid < 6250) {
        const size_t base = ((size_t)bid * 256 + threadIdx.x) * 8;
        const float4* xp = (const float4*)(x + base);
        const float4 a = xp[0], b = xp[1];
        half8 v;
        v[0] = (_Float16)a.x; v[1] = (_Float16)a.y;
        v[2] = (_Float16)a.z; v[3] = (_Float16)a.w;
        v[4] = (_Float16)b.x; v[5] = (_Float16)b.y;
        v[6] = (_Float16)b.z; v[7] = (_Float16)b.w;
        *(half8*)(xh + base) = v;
    } else if (bid < 6282) {
        // W[256][128] -> f16 B-fragment order for mfma_f32_16x16x32_f16:
        // frag (kb,nb,lane): B[k=kb*32+(lane>>4)*8+j][n=nb*16+(lane&15)]
        const int tid = (bid - 6250) * 256 + threadIdx.x;  // [0, 8192)
        const int which = tid >> 12;
        const int r = tid & 4095;
        const int kb = r >> 9, nb = (r >> 6) & 7, lane = r & 63;
        const int q = lane >> 4, c = lane & 15;
        const float* W = which ? W2 : W1;
        _Float16* O = which ? W2sw : W1sw;
        const int k0 = kb * 32 + q * 8;
        const int n = nb * 16 + c;
        half8 v;
#pragma unroll
        for (int j = 0; j < 8; ++j) v[j] = (_Float16)W[(size_t)(k0 + j) * DIM + n];
        *(half8*)(O + (size_t)r * 8) = v;
    } else {
        const int j = (bid - 6282) * 256 + threadIdx.x;
        if (j < NBATCH) {
            const int b = batch[j];
            flags[b] = 1;
            const int* row = nidx + (size_t)b * SAMPLES;
#pragma unroll
            for (int s = 0; s < SAMPLES; ++s) flags[row[s]] = 1;
        }
    }
}

// layer1: block = 256 threads = 16 nodes. 16-lane group g gathers node
// blockIdx*16+g, lane cl = one 16B chunk of the 256B row -> full-row
// coalesced reads.
//
// Gather structure (round-3 post-mortem): the win mechanism is LOW REGISTER
// PRESSURE -> 8 waves/SIMD residency, NOT address locality (FETCH was
// unchanged by sorting). So: no sort (saves ~126 VALU ops/lane), and a
// 4-deep x 4-round accumulate — 4 loads in flight per lane (vs round-3's 2)
// halves the serial-latency chain while keeping live regs ~52 (<64, the
// 8-waves/SIMD cliff). sched_barrier(0) between rounds stops the compiler
// from hoisting into a 16-deep/64-reg burst.
__global__ __launch_bounds__(256) void layer1_kernel(
    const _Float16* __restrict__ xh,
    const int* __restrict__ nidx,
    const _Float16* __restrict__ W1sw,
    const float* __restrict__ b1,
    const int* __restrict__ flags,
    _Float16* __restrict__ h1h) {
    const int t = threadIdx.x;
    const int g = t >> 4;        // node slot 0..15
    const int cl = t & 15;       // 16B chunk 0..15
    const int i0 = blockIdx.x * 16;
    const int i = i0 + g;        // 6250*16 == 100000 exactly

    __shared__ __align__(16) _Float16 feats[16 * FSTR];

    const bool fi = (flags[i] == 1);
    if (fi) {
        const char* xb = (const char*)xh;
        const int cb = cl * 16;
        const half8 self = *(const half8*)(xb + (size_t)i * 256 + cb);
        const int4* ip = (const int4*)(nidx + (size_t)i * SAMPLES);
        const int4 a0 = ip[0], a1 = ip[1], a2 = ip[2], a3 = ip[3];
        int off[16];
        off[0]  = a0.x * 256 + cb; off[1]  = a0.y * 256 + cb;
        off[2]  = a0.z * 256 + cb; off[3]  = a0.w * 256 + cb;
        off[4]  = a1.x * 256 + cb; off[5]  = a1.y * 256 + cb;
        off[6]  = a1.z * 256 + cb; off[7]  = a1.w * 256 + cb;
        off[8]  = a2.x * 256 + cb; off[9]  = a2.y * 256 + cb;
        off[10] = a2.z * 256 + cb; off[11] = a2.w * 256 + cb;
        off[12] = a3.x * 256 + cb; off[13] = a3.y * 256 + cb;
        off[14] = a3.z * 256 + cb; off[15] = a3.w * 256 + cb;
        half8 acc;
        {
            const half8 v0 = *(const half8*)(xb + off[0]);
            const half8 v1 = *(const half8*)(xb + off[1]);
            const half8 v2 = *(const half8*)(xb + off[2]);
            const half8 v3 = *(const half8*)(xb + off[3]);
            acc = h8max(h8max(v0, v1), h8max(v2, v3));
        }
#pragma unroll
        for (int bp = 1; bp < 4; ++bp) {
            __builtin_amdgcn_sched_barrier(0);
            const half8 v0 = *(const half8*)(xb + off[4 * bp]);
            const half8 v1 = *(const half8*)(xb + off[4 * bp + 1]);
            const half8 v2 = *(const half8*)(xb + off[4 * bp + 2]);
            const half8 v3 = *(const half8*)(xb + off[4 * bp + 3]);
            acc = h8max(acc, h8max(h8max(v0, v1), h8max(v2, v3)));
        }
        *(half8*)(feats + g * FSTR + cl * 8) = self;
        *(half8*)(feats + g * FSTR + DIM + cl * 8) = acc;
    } else {
        half8 z;
#pragma unroll
        for (int e = 0; e < 8; ++e) z[e] = (_Float16)0.f;
        *(half8*)(feats + g * FSTR + cl * 8) = z;
        *(half8*)(feats + g * FSTR + DIM + cl * 8) = z;
    }
    __syncthreads();

    // MFMA: wave w computes nb = 2w, 2w+1 over K=256.
    // A[m=c][k=kb*32+q*8+j] from LDS; B from pre-swizzled W1; D[m=q*4+r][n=nb*16+c]
    const int wave = t >> 6;
    const int lane = t & 63;
    const int q = lane >> 4, c = lane & 15;
    const int nb0 = wave * 2;
    floatx4 acc[2];
    acc[0] = (floatx4){0.f, 0.f, 0.f, 0.f};
    acc[1] = (floatx4){0.f, 0.f, 0.f, 0.f};
#pragma unroll
    for (int kb = 0; kb < 8; ++kb) {
        const half8 a = *(const half8*)(feats + c * FSTR + kb * 32 + q * 8);
#pragma unroll
        for (int j = 0; j < 2; ++j) {
            const half8 b = *(const half8*)(W1sw + (size_t)((kb * 8 + nb0 + j) * 64 + lane) * 8);
            acc[j] = __builtin_amdgcn_mfma_f32_16x16x32_f16(a, b, acc[j], 0, 0, 0);
        }
    }

    // epilogue: bias + relu + non-temporal f16 store, gated per stored row
#pragma unroll
    for (int r = 0; r < 4; ++r) {
        const int node = i0 + q * 4 + r;
        if (flags[node] != 1) continue;
#pragma unroll
        for (int j = 0; j < 2; ++j) {
            const int n = (nb0 + j) * 16 + c;
            const float v = fmaxf(acc[j][r] + b1[n], 0.f);
            const _Float16 hv = (_Float16)v;
            __builtin_nontemporal_store(hv, h1h + (size_t)node * DIM + n);
        }
    }
}

// Cooperative layer2, 512 threads / 16 batch rows (was 256): layer2 runs only
// 512 blocks (2/CU) so it is the lowest-TLP kernel in the pipeline; doubling
// waves per block doubles resident waves per CU at identical traffic.
// Gather: 32 lanes per node, 8B (half4) chunks -> still full-256B coalesced
// row reads; 4-deep x 4-round accumulate as in layer1.
// MFMA: 8 waves, each computes ONE n-block nb == wave.
// proj_out: 8 waves x 2 rows.
__global__ __launch_bounds__(512) void layer2_kernel(
    const _Float16* __restrict__ h1h,
    const int* __restrict__ nidx,
    const int* __restrict__ batch,
    const _Float16* __restrict__ W2sw,
    const float* __restrict__ b2,
    const float* __restrict__ Wout,
    const float* __restrict__ bout,
    float* __restrict__ out) {
    const int t = threadIdx.x;
    const int wave = t >> 6;     // 0..7
    const int lane = t & 63;
    const int q = lane >> 4, c = lane & 15;
    const int w0 = blockIdx.x * 16;

    __shared__ __align__(16) _Float16 feats[16 * FSTR];
    __shared__ __align__(16) float h2s[16 * H2STR];

    // ---- gather: 32 lanes per node, 8B chunks ----
    {
        const int m = t >> 5;    // node slot 0..15
        const int cl = t & 31;   // 8B chunk 0..31
        const int node = batch[w0 + m];
        const char* hb = (const char*)h1h;
        const int cb = cl * 8;
        const half4 self = *(const half4*)(hb + (size_t)node * 256 + cb);
        const int4* ip = (const int4*)(nidx + (size_t)node * SAMPLES);
        const int4 a0 = ip[0], a1 = ip[1], a2 = ip[2], a3 = ip[3];
        int off[16];
        off[0]  = a0.x * 256 + cb; off[1]  = a0.y * 256 + cb;
        off[2]  = a0.z * 256 + cb; off[3]  = a0.w * 256 + cb;
        off[4]  = a1.x * 256 + cb; off[5]  = a1.y * 256 + cb;
        off[6]  = a1.z * 256 + cb; off[7]  = a1.w * 256 + cb;
        off[8]  = a2.x * 256 + cb; off[9]  = a2.y * 256 + cb;
        off[10] = a2.z * 256 + cb; off[11] = a2.w * 256 + cb;
        off[12] = a3.x * 256 + cb; off[13] = a3.y * 256 + cb;
        off[14] = a3.z * 256 + cb; off[15] = a3.w * 256 + cb;
        half4 acc;
        {
            const half4 v0 = *(const half4*)(hb + off[0]);
            const half4 v1 = *(const half4*)(hb + off[1]);
            const half4 v2 = *(const half4*)(hb + off[2]);
            const half4 v3 = *(const half4*)(hb + off[3]);
            acc = h4max(h4max(v0, v1), h4max(v2, v3));
        }
#pragma unroll
        for (int bp = 1; bp < 4; ++bp) {
            __builtin_amdgcn_sched_barrier(0);
            const half4 v0 = *(const half4*)(hb + off[4 * bp]);
            const half4 v1 = *(const half4*)(hb + off[4 * bp + 1]);
            const half4 v2 = *(const half4*)(hb + off[4 * bp + 2]);
            const half4 v3 = *(const half4*)(hb + off[4 * bp + 3]);
            acc = h4max(acc, h4max(h4max(v0, v1), h4max(v2, v3)));
        }
        *(half4*)(feats + m * FSTR + cl * 4) = self;
        *(half4*)(feats + m * FSTR + DIM + cl * 4) = acc;
    }
    __syncthreads();

    // ---- MFMA: each wave computes nb == wave over K=256 ----
    floatx4 acc;
    acc = (floatx4){0.f, 0.f, 0.f, 0.f};
#pragma unroll
    for (int kb = 0; kb < 8; ++kb) {
        const half8 a = *(const half8*)(feats + c * FSTR + kb * 32 + q * 8);
        const half8 b = *(const half8*)(W2sw + (size_t)((kb * 8 + wave) * 64 + lane) * 8);
        acc = __builtin_amdgcn_mfma_f32_16x16x32_f16(a, b, acc, 0, 0, 0);
    }
    {
        const int n = wave * 16 + c;
        const float bias = b2[n];
#pragma unroll
        for (int r = 0; r < 4; ++r)
            h2s[(q * 4 + r) * H2STR + n] = acc[r] + bias;
    }
    __syncthreads();

    // ---- proj_out: wave handles rows wave*2, wave*2+1; lane = output dim ----
    float accs[2];
    const float bo = bout[lane];
#pragma unroll
    for (int r = 0; r < 2; ++r) accs[r] = bo;
    for (int k4 = 0; k4 < DIM; k4 += 4) {
        float wv[4];
#pragma unroll
        for (int j = 0; j < 4; ++j) wv[j] = Wout[(size_t)(k4 + j) * 64 + lane];
#pragma unroll
        for (int r = 0; r < 2; ++r) {
            const float4 f = *(const float4*)&h2s[(wave * 2 + r) * H2STR + k4];
            accs[r] += f.x * wv[0] + f.y * wv[1] + f.z * wv[2] + f.w * wv[3];
        }
    }
#pragma unroll
    for (int r = 0; r < 2; ++r)
        __builtin_nontemporal_store(accs[r], out + (size_t)(w0 + wave * 2 + r) * 64 + lane);
}

extern "C" void kernel_launch(void* const* d_in, const int* in_sizes, int n_in,
                              void* d_out, int out_size, void* d_ws, size_t ws_size,
                              hipStream_t stream) {
    const float* x    = (const float*)d_in[0];
    const int* nidx   = (const int*)d_in[1];
    const int* batch  = (const int*)d_in[2];
    const float* W1   = (const float*)d_in[3];
    const float* b1   = (const float*)d_in[4];
    const float* W2   = (const float*)d_in[5];
    const float* b2   = (const float*)d_in[6];
    const float* Wout = (const float*)d_in[7];
    const float* bout = (const float*)d_in[8];
    float* out        = (float*)d_out;

    // ws layout (bytes):
    //   [0, 400000)           flags (poison-based: flagged == 1)
    //   [409600, 475136)      W1sw f16
    //   [475136, 540672)      W2sw f16
    //   [540672, 26140672)    xh   f16
    //   [26140672, 51740672)  h1h  f16
    int* flags      = (int*)d_ws;
    _Float16* W1sw  = (_Float16*)((char*)d_ws + 409600);
    _Float16* W2sw  = (_Float16*)((char*)d_ws + 475136);
    _Float16* xh    = (_Float16*)((char*)d_ws + 540672);
    _Float16* h1h   = (_Float16*)((char*)d_ws + 26140672);

    setup_kernel<<<6314, 256, 0, stream>>>(x, W1, W2, batch, nidx, flags, xh, W1sw, W2sw);
    layer1_kernel<<<N_NODES / 16, 256, 0, stream>>>(xh, nidx, W1sw, b1, flags, h1h);
    layer2_kernel<<<NBATCH / 16, 512, 0, stream>>>(h1h, nidx, batch, W2sw, b2, Wout, bout, out);
}